// Round 8
// baseline (752.643 us; speedup 1.0000x reference)
//
#include <hip/hip_runtime.h>

// Problem constants (B, H, W) from the reference.
#define BB 8
#define HH 1080
#define WW 1920
constexpr int HWc  = HH * WW;          // 2,073,600
constexpr int Ntot = BB * HWc;         // 16,588,800

constexpr int TILE = 64;               // OUTPUT core side (exclusive per block)
constexpr int MAR  = 32;               // gather margin: P(|N(0,10)| > 32) ~ 7e-4 per tail
constexpr int REG  = TILE + 2 * MAR;   // 128 -> source window 128x128
constexpr int WT   = WW / TILE;        // 30 (exact)
constexpr int HT   = (HH + TILE - 1) / TILE;  // 17 (last core partial: rows 1024..1079)
constexpr int NTILE = WT * HT;         // 510 tiles per image
constexpr int GT    = NTILE * BB;      // 4080 tiles total
constexpr int CAP   = 256;             // spill records per tile (avg ~60 when present)

// S-plane: corner-anchor accumulator. S[r][c] = sum of v over sources whose
// top-left corner (iyT,ixL) = (Y0-1+r, X0-1+c). Output cell = 2x2 box of S.
// Measured (R1/R2/R3 fit): tile_k ~= 55us + 80us per atomic-lane-op/source;
// 3 lane-ops/source (one per channel) is the algorithmic minimum.
constexpr int SDIM = 65;               // rows/cols Y0-1 .. Y0+63
constexpr int SSTR = 66;               // stride (row step shifts banks by 2)
constexpr int PL   = SSTR * SSTR;      // 4356 floats per channel plane

static_assert(TILE == 64, "ownership test uses >>6");
static_assert((WW & 3) == 0 && (HWc & 3) == 0, "float4 groups must not straddle");
static_assert(3 * PL * 4 <= 53000, "need 3 blocks/CU");

// Workspace layout (~33.4 MB; ws proven >= 199 MB in earlier rounds):
//   [0)        cnt:     GT u32 spill counters (16,320 B; only memset)
//   [16384)    buckets: GT * CAP * float4 {cell_bits, vx, vy, w}   (16.7 MB)
//   [+]        mask:    Ntot bytes, 1 = pixel has weight           (16.6 MB)
constexpr size_t OFF_BKT  = 16384;
constexpr size_t OFF_MASK = OFF_BKT + (size_t)GT * CAP * 16;

// ---------------------------------------------------------------------------
// Spill append (rare): a corner whose owner tile's 128x128 window does NOT
// contain the source. Duplicate (clamped) corners produce duplicate records
// == reference's double-add. Gate: only called when |fx|>30 or |fy|>30.
// ---------------------------------------------------------------------------
__device__ inline void spill_append(int b, int xs, int ys, int ixL, int iyT,
                                    float fx, float fy, float w,
                                    unsigned* cnt, float4* buckets) {
    int ixR = min(ixL + 1, WW - 1);
    int iyB = min(iyT + 1, HH - 1);
    int cxs[2] = {ixL, ixR};
    int cys[2] = {iyT, iyB};
    float vx = -fx * w, vy = -fy * w;
#pragma unroll
    for (int a = 0; a < 2; ++a)
#pragma unroll
        for (int cc = 0; cc < 2; ++cc) {
            int cx = cxs[cc], cy = cys[a];
            int ox = (cx >> 6) * TILE - MAR;
            int oy = (cy >> 6) * TILE - MAR;
            if (!(xs >= ox && xs < ox + REG && ys >= oy && ys < oy + REG)) {
                int gtile = b * NTILE + (cy >> 6) * WT + (cx >> 6);
                unsigned slot = atomicAdd(&cnt[gtile], 1u);
                if (slot < (unsigned)CAP) {
                    float4 rec;
                    rec.x = __int_as_float(((cy & 63) << 6) | (cx & 63));
                    rec.y = vx; rec.z = vy; rec.w = w;
                    buckets[(size_t)gtile * CAP + slot] = rec;
                }
            }
        }
}

// ---------------------------------------------------------------------------
// Gather-tile kernel: one block (512 threads) per EXCLUSIVE 64x64 output core.
// Splat-once into S-plane (3 LDS atomics / source), spill discovery for core
// |f|>30 pixels, 2x2 box-sum writeback with divide; stores out planes + byte
// mask. (wplane dropped in R8 — fixup re-derives w0 by re-splatting.)
// ---------------------------------------------------------------------------
#define PROC(FXC, FYC, DWC, CGX)                                               \
    {                                                                          \
        float fx = (FXC), fy = (FYC);                                          \
        float x2 = (float)(CGX) + fx, y2 = gyf + fy;                           \
        if (x2 >= 0.f && x2 <= (float)(WW - 1) &&                              \
            y2 >= 0.f && y2 <= (float)(HH - 1)) {                              \
            int ixL = (int)floorf(x2);   /* validity bounds to [0,WW-1] */     \
            int iyT = (int)floorf(y2);                                         \
            unsigned cI = (unsigned)(ixL - (X0 - 1));                          \
            unsigned rI = (unsigned)(iyT - (Y0 - 1));                          \
            if (cI < (unsigned)SDIM && rI < (unsigned)SDIM) {                  \
                float w = (DWC);                                               \
                if (ixL == WW - 1) w += w;   /* duplicate corner: x clamp */   \
                if (iyT == HH - 1) w += w;   /* duplicate corner: y clamp */   \
                int cell = (int)(rI * SSTR + cI);                              \
                atomicAdd(&sm[cell],          -fx * w);                        \
                atomicAdd(&sm[cell + PL],     -fy * w);                        \
                atomicAdd(&sm[cell + 2 * PL], w);                              \
            }                                                                  \
            if (core && (fabsf(fx) > 30.f || fabsf(fy) > 30.f))                \
                spill_append(b, (CGX), gy, ixL, iyT, fx, fy, (DWC),            \
                             cnt, buckets);                                    \
        }                                                                      \
    }

__global__ __launch_bounds__(512, 6) void tile_k(const float* __restrict__ flow,
                                                 const float* __restrict__ depth,
                                                 unsigned* __restrict__ cnt,
                                                 float4* __restrict__ buckets,
                                                 float* __restrict__ out,
                                                 unsigned char* __restrict__ mask) {
    __shared__ float sm[3 * PL];       // 52.3 KB
    const int bid  = blockIdx.x;
    const int b    = bid & 7;          // image round-robin (XCD affinity heuristic)
    const int tile = bid >> 3;
    const int ty   = tile / WT;
    const int tx   = tile - ty * WT;
    const int X0 = tx * TILE, Y0 = ty * TILE;
    const int rx0 = X0 - MAR, ry0 = Y0 - MAR;
    const int tid = threadIdx.x;

    // zero LDS: 3267 float4 / 512 threads
    float4* sm4 = (float4*)sm;
    for (int i = tid; i < 3 * PL / 4; i += 512)
        sm4[i] = make_float4(0.f, 0.f, 0.f, 0.f);
    __syncthreads();

    const float* fxp = flow + (size_t)b * 2 * HWc;
    const float* fyp = fxp + HWc;
    const float* dp  = depth + (size_t)b * HWc;

    // splat: 8 iterations; each thread owns a fixed 4-pixel column group and
    // walks 16 rows/iter. float4 loads; 1-deep register prefetch pipeline.
    const int gx  = rx0 + ((tid & 31) << 2);       // group start (4-aligned)
    const bool xok = (unsigned)gx < (unsigned)WW;  // groups fully in/out in x
    const bool xin = (unsigned)(gx - X0) < (unsigned)TILE;
    int gy = ry0 + (tid >> 5);
    float4 cfx, cfy, cd;
    bool ok = xok && ((unsigned)gy < (unsigned)HH);
    if (ok) {
        int p = gy * WW + gx;
        cfx = *(const float4*)(fxp + p);
        cfy = *(const float4*)(fyp + p);
        cd  = *(const float4*)(dp + p);
    }
#pragma unroll
    for (int k = 0; k < 8; ++k) {
        float4 nfx, nfy, nd;
        bool nok = false;
        const int ngy = gy + 16;
        if (k < 7) {
            nok = xok && ((unsigned)ngy < (unsigned)HH);
            if (nok) {
                int np = ngy * WW + gx;
                nfx = *(const float4*)(fxp + np);
                nfy = *(const float4*)(fyp + np);
                nd  = *(const float4*)(dp + np);
            }
        }
        if (ok) {
            const float gyf = (float)gy;
            const bool core = xin && ((unsigned)(gy - Y0) < (unsigned)TILE);
            PROC(cfx.x, cfy.x, cd.x, gx)
            PROC(cfx.y, cfy.y, cd.y, gx + 1)
            PROC(cfx.z, cfy.z, cd.z, gx + 2)
            PROC(cfx.w, cfy.w, cd.w, gx + 3)
        }
        ok = nok; gy = ngy; cfx = nfx; cfy = nfy; cd = nd;
    }
    __syncthreads();

    // writeback: 2x2 box of S per output cell, divide, store out planes +
    // byte mask. Exclusive — no atomics, no merge.
    float* o0 = out + (size_t)b * 2 * HWc;
    float* o1 = o0 + HWc;
    unsigned char* mb = mask + (size_t)b * HWc;
#pragma unroll
    for (int k = 0; k < 2; ++k) {              // 1024 float4 groups / 512 threads
        int j   = k * 512 + tid;               // cell group: cells 4j..4j+3
        int row = j >> 4;                      // core row 0..63
        int gy2 = Y0 + row;
        if (gy2 < HH) {
            int c0 = (j & 15) << 2;            // core col of lane .x
            int q  = gy2 * WW + X0 + c0;
            const int rA = (row + 1) * SSTR + c0;   // S[row+1][c0 ..]
            const int rB = row * SSTR + c0;         // S[row  ][c0 ..]
            float4 vx, vy, wv;
            {
                float a_0 = sm[rA], a_1 = sm[rA+1], a_2 = sm[rA+2], a_3 = sm[rA+3], a_4 = sm[rA+4];
                float b_0 = sm[rB], b_1 = sm[rB+1], b_2 = sm[rB+2], b_3 = sm[rB+3], b_4 = sm[rB+4];
                vx.x = a_0+a_1+b_0+b_1; vx.y = a_1+a_2+b_1+b_2;
                vx.z = a_2+a_3+b_2+b_3; vx.w = a_3+a_4+b_3+b_4;
            }
            {
                const int oA = rA + PL, oB = rB + PL;
                float a_0 = sm[oA], a_1 = sm[oA+1], a_2 = sm[oA+2], a_3 = sm[oA+3], a_4 = sm[oA+4];
                float b_0 = sm[oB], b_1 = sm[oB+1], b_2 = sm[oB+2], b_3 = sm[oB+3], b_4 = sm[oB+4];
                vy.x = a_0+a_1+b_0+b_1; vy.y = a_1+a_2+b_1+b_2;
                vy.z = a_2+a_3+b_2+b_3; vy.w = a_3+a_4+b_3+b_4;
            }
            {
                const int oA = rA + 2 * PL, oB = rB + 2 * PL;
                float a_0 = sm[oA], a_1 = sm[oA+1], a_2 = sm[oA+2], a_3 = sm[oA+3], a_4 = sm[oA+4];
                float b_0 = sm[oB], b_1 = sm[oB+1], b_2 = sm[oB+2], b_3 = sm[oB+3], b_4 = sm[oB+4];
                wv.x = a_0+a_1+b_0+b_1; wv.y = a_1+a_2+b_1+b_2;
                wv.z = a_2+a_3+b_2+b_3; wv.w = a_3+a_4+b_3+b_4;
            }
            float i0 = wv.x > 0.f ? 1.f / wv.x : 0.f;
            float i1 = wv.y > 0.f ? 1.f / wv.y : 0.f;
            float i2 = wv.z > 0.f ? 1.f / wv.z : 0.f;
            float i3 = wv.w > 0.f ? 1.f / wv.w : 0.f;
            float4 r0, r1;
            r0.x = vx.x * i0; r0.y = vx.y * i1; r0.z = vx.z * i2; r0.w = vx.w * i3;
            r1.x = vy.x * i0; r1.y = vy.y * i1; r1.z = vy.z * i2; r1.w = vy.w * i3;
            *(float4*)(o0 + q) = r0;
            *(float4*)(o1 + q) = r1;
            uchar4 mk;
            mk.x = (unsigned char)(wv.x > 0.f);
            mk.y = (unsigned char)(wv.y > 0.f);
            mk.z = (unsigned char)(wv.z > 0.f);
            mk.w = (unsigned char)(wv.w > 0.f);
            *(uchar4*)(mb + q) = mk;           // q % 4 == 0 by construction
        }
    }
}

// ---------------------------------------------------------------------------
// Fixup: merge spill records into the finalized output. One block per tile;
// ~99% of blocks read cnt==0 and exit before any barrier (block-uniform).
// Active blocks (~30): combine records by cell in LDS, RE-SPLAT this tile's
// window w-channel to recover pre-spill w0 for touched cells (replaces the
// 66 MB wplane), then renormalize exactly:
//   out_new = (out_old * w0 + sum_v) / (w0 + sum_w).
// Anchor->cell mapping: source anchored at (ar,ac) feeds cells
// (ar..ar+1)x(ac..ac+1); in-core cells only. Clamp doubling via wEff.
// ---------------------------------------------------------------------------
__global__ __launch_bounds__(256) void fixup_k(const unsigned* __restrict__ cnt,
                                               const float4* __restrict__ buckets,
                                               const float* __restrict__ flow,
                                               const float* __restrict__ depth,
                                               float* __restrict__ out,
                                               unsigned char* __restrict__ mask) {
    __shared__ float s[4 * 4096];      // 64 KB: {svx, svy, sw, w0}
    int gtile = blockIdx.x;
    unsigned n = cnt[gtile];
    if (n == 0) return;
    if (n > (unsigned)CAP) n = CAP;
    int b  = gtile / NTILE;
    int t  = gtile - b * NTILE;
    int ty = t / WT, tx = t - ty * WT;
    int X0 = tx * TILE, Y0 = ty * TILE;
    const int rx0 = X0 - MAR, ry0 = Y0 - MAR;

    float4* s4 = (float4*)s;
    for (int i = threadIdx.x; i < 4 * 4096 / 4; i += 256)
        s4[i] = make_float4(0.f, 0.f, 0.f, 0.f);
    __syncthreads();

    // combine spill records by cell
    const float4* bkt = buckets + (size_t)gtile * CAP;
    for (unsigned r = threadIdx.x; r < n; r += 256) {
        float4 rec = bkt[r];
        int cell = __float_as_int(rec.x);
        atomicAdd(&s[cell],        rec.y);
        atomicAdd(&s[cell + 4096], rec.z);
        atomicAdd(&s[cell + 8192], rec.w);
    }
    __syncthreads();

    // re-splat w over this tile's window: recover w0 for touched cells.
    const float* fxp = flow + (size_t)b * 2 * HWc;
    const float* fyp = fxp + HWc;
    const float* dp  = depth + (size_t)b * HWc;
    for (int k = 0; k < 16; ++k) {
        int i  = k * 256 + threadIdx.x;        // float4 group in window
        int gy = ry0 + (i >> 5);
        int gx = rx0 + ((i & 31) << 2);
        if ((unsigned)gy < (unsigned)HH && (unsigned)gx < (unsigned)WW) {
            int p = gy * WW + gx;
            float4 fx4 = *(const float4*)(fxp + p);
            float4 fy4 = *(const float4*)(fyp + p);
            float4 d4  = *(const float4*)(dp + p);
            const float fxs[4] = {fx4.x, fx4.y, fx4.z, fx4.w};
            const float fys[4] = {fy4.x, fy4.y, fy4.z, fy4.w};
            const float ds[4]  = {d4.x, d4.y, d4.z, d4.w};
#pragma unroll
            for (int c = 0; c < 4; ++c) {
                float fx = fxs[c], fy = fys[c];
                float x2 = (float)(gx + c) + fx, y2 = (float)gy + fy;
                if (x2 >= 0.f && x2 <= (float)(WW - 1) &&
                    y2 >= 0.f && y2 <= (float)(HH - 1)) {
                    int ac = (int)floorf(x2);
                    int ar = (int)floorf(y2);
                    float wEff = ds[c];
                    if (ac == WW - 1) wEff += wEff;
                    if (ar == HH - 1) wEff += wEff;
#pragma unroll
                    for (int dy = 0; dy < 2; ++dy)
#pragma unroll
                        for (int dx = 0; dx < 2; ++dx) {
                            unsigned ur = (unsigned)(ar + dy - Y0);
                            unsigned uc = (unsigned)(ac + dx - X0);
                            if (ur < (unsigned)TILE && uc < (unsigned)TILE) {
                                int cell = (int)((ur << 6) | uc);
                                if (s[cell + 8192] != 0.f)   // touched only
                                    atomicAdd(&s[cell + 12288], wEff);
                            }
                        }
                }
            }
        }
    }
    __syncthreads();

    float* o0 = out + (size_t)b * 2 * HWc;
    float* o1 = o0 + HWc;
    unsigned char* mb = mask + (size_t)b * HWc;
    for (int cell = threadIdx.x; cell < 4096; cell += 256) {
        float ws = s[cell + 8192];
        if (ws != 0.f) {               // depth > 0.1 -> every record has w > 0
            int cy = Y0 + (cell >> 6), cx = X0 + (cell & 63);
            if (cy < HH) {
                int q = cy * WW + cx;
                float w0 = s[cell + 12288];
                float wn = w0 + ws;
                float v0 = o0[q] * w0 + s[cell];
                float v1 = o1[q] * w0 + s[cell + 4096];
                float inv = wn > 0.f ? 1.f / wn : 0.f;
                o0[q] = v0 * inv;
                o1[q] = v1 * inv;
                mb[q] = 1;
            }
        }
    }
}

// ---------------------------------------------------------------------------
// Hole fill, LDS-windowed (unchanged from R7): one block per 64x64 core,
// stage the 128x128 mask window, scan in LDS; exact global fallback for
// exhausted scans (P ~ 0.02^32, preserves reference semantics).
// ---------------------------------------------------------------------------
constexpr int FWW = 128;               // fill window side
__global__ __launch_bounds__(256) void fill_k(float* __restrict__ out,
                                              const unsigned char* __restrict__ mask) {
    __shared__ unsigned char wm[FWW * FWW];    // 16 KB
    const int bid  = blockIdx.x;
    const int b    = bid & 7;
    const int tile = bid >> 3;
    const int ty   = tile / WT;
    const int tx   = tile - ty * WT;
    const int X0 = tx * TILE, Y0 = ty * TILE;
    const int wx0 = X0 - 32, wy0 = Y0 - 32;
    const int tid = threadIdx.x;

    const unsigned char* mb = mask + (size_t)b * HWc;

    // stage window: thread -> (row r = tid>>1, 64B half h = tid&1)
    {
        int r  = tid >> 1, h = tid & 1;
        int wy = wy0 + r;
        int xs = wx0 + h * 64;                 // multiple of 32 -> 16B aligned
        unsigned char* dst = &wm[r * FWW + h * 64];
        if ((unsigned)wy >= (unsigned)HH) {
            uint4 z = make_uint4(0u, 0u, 0u, 0u);
            uint4* d4 = (uint4*)dst;
            d4[0] = z; d4[1] = z; d4[2] = z; d4[3] = z;
        } else if (xs >= 0 && xs + 64 <= WW) {
            const uint4* s4 = (const uint4*)(mb + (size_t)wy * WW + xs);
            uint4* d4 = (uint4*)dst;
            d4[0] = s4[0]; d4[1] = s4[1]; d4[2] = s4[2]; d4[3] = s4[3];
        } else {
            for (int i = 0; i < 64; ++i) {
                int gxx = xs + i;
                dst[i] = ((unsigned)gxx < (unsigned)WW)
                             ? mb[(size_t)wy * WW + gxx] : (unsigned char)0;
            }
        }
    }
    __syncthreads();

    const float* o0 = out + (size_t)b * 2 * HWc;
    const float* o1 = o0 + HWc;

    // 4096 core pixels / 256 threads = 16 each; wave-aligned rows.
    for (int k = 0; k < 16; ++k) {
        int ci = k * 256 + tid;
        int ry = ci >> 6, cx = ci & 63;
        int gy = Y0 + ry;
        if (gy >= HH) continue;
        int wr = ry + 32, wc = cx + 32;
        if (wm[wr * FWW + wc]) continue;       // filled -> skip

        int gxp = X0 + cx;
        float s = 0.f, s0 = 0.f, s1 = 0.f;

        // LEFT
        {
            int f = -1;
            for (int j = wc - 1; j >= 0; --j)
                if (wm[wr * FWW + j]) { f = wx0 + j; break; }
            if (f < 0 && wx0 > 0)              // exhausted window (rare)
                for (int j = wx0 - 1; j >= 0; --j)
                    if (mb[(size_t)gy * WW + j]) { f = j; break; }
            if (f >= 0) { int q = gy * WW + f; s += 1.f; s0 += o0[q]; s1 += o1[q]; }
        }
        // RIGHT (window zero-padded beyond WW -> pad never matches)
        {
            int f = -1;
            for (int j = wc + 1; j < FWW; ++j)
                if (wm[wr * FWW + j]) { f = wx0 + j; break; }
            if (f < 0 && wx0 + FWW < WW)
                for (int j = wx0 + FWW; j < WW; ++j)
                    if (mb[(size_t)gy * WW + j]) { f = j; break; }
            if (f >= 0) { int q = gy * WW + f; s += 1.f; s0 += o0[q]; s1 += o1[q]; }
        }
        // UP
        {
            int f = -1;
            for (int i = wr - 1; i >= 0; --i)
                if (wm[i * FWW + wc]) { f = wy0 + i; break; }
            if (f < 0 && wy0 > 0)
                for (int i = wy0 - 1; i >= 0; --i)
                    if (mb[(size_t)i * WW + gxp]) { f = i; break; }
            if (f >= 0) { int q = f * WW + gxp; s += 1.f; s0 += o0[q]; s1 += o1[q]; }
        }
        // DOWN (window zero-padded beyond HH -> pad never matches)
        {
            int f = -1;
            for (int i = wr + 1; i < FWW; ++i)
                if (wm[i * FWW + wc]) { f = wy0 + i; break; }
            if (f < 0 && wy0 + FWW < HH)
                for (int i = wy0 + FWW; i < HH; ++i)
                    if (mb[(size_t)i * WW + gxp]) { f = i; break; }
            if (f >= 0) { int q = f * WW + gxp; s += 1.f; s0 += o0[q]; s1 += o1[q]; }
        }

        if (s > 0.f) {
            int p = gy * WW + gxp;
            ((float*)o0)[p] = s0 / s;
            ((float*)o1)[p] = s1 / s;
        }
    }
}

extern "C" void kernel_launch(void* const* d_in, const int* in_sizes, int n_in,
                              void* d_out, int out_size, void* d_ws, size_t ws_size,
                              hipStream_t stream) {
    const float* flow  = (const float*)d_in[0];   // (B,2,H,W)
    const float* depth = (const float*)d_in[1];   // (B,1,H,W)
    float* out = (float*)d_out;                   // (B,2,H,W)

    unsigned char* wsb = (unsigned char*)d_ws;
    unsigned* cnt       = (unsigned*)wsb;
    float4*  buckets    = (float4*)(wsb + OFF_BKT);
    unsigned char* mask = wsb + OFF_MASK;

    const int threads = 256;

    // only memset: 16 KB of spill counters
    hipMemsetAsync(cnt, 0, (size_t)GT * sizeof(unsigned), stream);

    // fused: splat + spill discovery + average + mask
    tile_k<<<GT, 512, 0, stream>>>(flow, depth, cnt, buckets, out, mask);

    // merge rare spill records; re-derives w0 by window re-splat (no wplane)
    fixup_k<<<GT, threads, 0, stream>>>(cnt, buckets, flow, depth, out, mask);

    // LDS-windowed hole fill
    fill_k<<<GT, threads, 0, stream>>>(out, mask);
}

// Round 9
// 595.165 us; speedup vs baseline: 1.2646x; 1.2646x over previous
//
#include <hip/hip_runtime.h>

// Problem constants (B, H, W) from the reference.
#define BB 8
#define HH 1080
#define WW 1920
constexpr int HWc  = HH * WW;          // 2,073,600
constexpr int Ntot = BB * HWc;         // 16,588,800

constexpr int TILE = 64;               // OUTPUT core side (exclusive per block)
constexpr int MAR  = 32;               // gather margin: P(|N(0,10)| > 32) ~ 7e-4 per tail
constexpr int REG  = TILE + 2 * MAR;   // 128 -> source window 128x128
constexpr int WT   = WW / TILE;        // 30 (exact)
constexpr int HT   = (HH + TILE - 1) / TILE;  // 17 (last core partial: rows 1024..1079)
constexpr int NTILE = WT * HT;         // 510 tiles per image
constexpr int GT    = NTILE * BB;      // 4080 tiles total
constexpr int CAP   = 256;             // spill records per tile (mean ~4; Poisson tail ~0)

// S-plane: corner-anchor accumulator. S[r][c] = sum of v over sources whose
// top-left corner (iyT,ixL) = (Y0-1+r, X0-1+c). Output cell = 2x2 box of S.
// Measured: tile_k ~= 55us + 80us per atomic-lane-op/source; 3 lane-ops/source
// is the algorithmic minimum (R8 proved duration is write-BW-insensitive).
constexpr int SDIM = 65;               // rows/cols Y0-1 .. Y0+63
constexpr int SSTR = 66;               // stride (row step shifts banks by 2)
constexpr int PL   = SSTR * SSTR;      // 4356 floats per channel plane

static_assert(TILE == 64, "ownership test uses >>6");
static_assert((WW & 3) == 0 && (HWc & 3) == 0, "float4 groups must not straddle");
static_assert(3 * PL * 4 <= 53000, "need 3 blocks/CU");

// Workspace layout (~100 MB; ws proven >= 199 MB in earlier rounds):
//   [0)        cnt:     GT u32 spill counters (16,320 B; only memset)
//   [16384)    buckets: GT * CAP * float4 {cell_bits, vx, vy, w}   (16.7 MB)
//   [+]        mask:    Ntot bytes, 1 = pixel has weight           (16.6 MB)
//   [+]        wplane:  Ntot floats, final per-pixel weight sum    (66.4 MB)
constexpr size_t OFF_BKT  = 16384;
constexpr size_t OFF_MASK = OFF_BKT + (size_t)GT * CAP * 16;
constexpr size_t OFF_W    = OFF_MASK + (size_t)Ntot;   // 16-aligned (checked)
static_assert(OFF_W % 16 == 0, "wplane must be float4-aligned");

// ---------------------------------------------------------------------------
// Spill append (rare): a corner whose owner tile's 128x128 window does NOT
// contain the source. Duplicate (clamped) corners produce duplicate records
// == reference's double-add. Gate: only called when |fx|>30 or |fy|>30.
// ---------------------------------------------------------------------------
__device__ inline void spill_append(int b, int xs, int ys, int ixL, int iyT,
                                    float fx, float fy, float w,
                                    unsigned* cnt, float4* buckets) {
    int ixR = min(ixL + 1, WW - 1);
    int iyB = min(iyT + 1, HH - 1);
    int cxs[2] = {ixL, ixR};
    int cys[2] = {iyT, iyB};
    float vx = -fx * w, vy = -fy * w;
#pragma unroll
    for (int a = 0; a < 2; ++a)
#pragma unroll
        for (int cc = 0; cc < 2; ++cc) {
            int cx = cxs[cc], cy = cys[a];
            int ox = (cx >> 6) * TILE - MAR;
            int oy = (cy >> 6) * TILE - MAR;
            if (!(xs >= ox && xs < ox + REG && ys >= oy && ys < oy + REG)) {
                int gtile = b * NTILE + (cy >> 6) * WT + (cx >> 6);
                unsigned slot = atomicAdd(&cnt[gtile], 1u);
                if (slot < (unsigned)CAP) {
                    float4 rec;
                    rec.x = __int_as_float(((cy & 63) << 6) | (cx & 63));
                    rec.y = vx; rec.z = vy; rec.w = w;
                    buckets[(size_t)gtile * CAP + slot] = rec;
                }
            }
        }
}

// ---------------------------------------------------------------------------
// Gather-tile kernel (R7-proven): one block (512 threads) per EXCLUSIVE 64x64
// output core. Splat-once into S-plane (3 LDS atomics / source), spill
// discovery for core |f|>30 pixels, 2x2 box-sum writeback with divide; stores
// out planes + w-plane + byte mask. (R8 proved the w-plane write is free.)
// ---------------------------------------------------------------------------
#define PROC(FXC, FYC, DWC, CGX)                                               \
    {                                                                          \
        float fx = (FXC), fy = (FYC);                                          \
        float x2 = (float)(CGX) + fx, y2 = gyf + fy;                           \
        if (x2 >= 0.f && x2 <= (float)(WW - 1) &&                              \
            y2 >= 0.f && y2 <= (float)(HH - 1)) {                              \
            int ixL = (int)floorf(x2);   /* validity bounds to [0,WW-1] */     \
            int iyT = (int)floorf(y2);                                         \
            unsigned cI = (unsigned)(ixL - (X0 - 1));                          \
            unsigned rI = (unsigned)(iyT - (Y0 - 1));                          \
            if (cI < (unsigned)SDIM && rI < (unsigned)SDIM) {                  \
                float w = (DWC);                                               \
                if (ixL == WW - 1) w += w;   /* duplicate corner: x clamp */   \
                if (iyT == HH - 1) w += w;   /* duplicate corner: y clamp */   \
                int cell = (int)(rI * SSTR + cI);                              \
                atomicAdd(&sm[cell],          -fx * w);                        \
                atomicAdd(&sm[cell + PL],     -fy * w);                        \
                atomicAdd(&sm[cell + 2 * PL], w);                              \
            }                                                                  \
            if (core && (fabsf(fx) > 30.f || fabsf(fy) > 30.f))                \
                spill_append(b, (CGX), gy, ixL, iyT, fx, fy, (DWC),            \
                             cnt, buckets);                                    \
        }                                                                      \
    }

__global__ __launch_bounds__(512, 6) void tile_k(const float* __restrict__ flow,
                                                 const float* __restrict__ depth,
                                                 unsigned* __restrict__ cnt,
                                                 float4* __restrict__ buckets,
                                                 float* __restrict__ out,
                                                 unsigned char* __restrict__ mask,
                                                 float* __restrict__ wplane) {
    __shared__ float sm[3 * PL];       // 52.3 KB
    const int bid  = blockIdx.x;
    const int b    = bid & 7;          // image round-robin (XCD affinity heuristic)
    const int tile = bid >> 3;
    const int ty   = tile / WT;
    const int tx   = tile - ty * WT;
    const int X0 = tx * TILE, Y0 = ty * TILE;
    const int rx0 = X0 - MAR, ry0 = Y0 - MAR;
    const int tid = threadIdx.x;

    // zero LDS: 3267 float4 / 512 threads
    float4* sm4 = (float4*)sm;
    for (int i = tid; i < 3 * PL / 4; i += 512)
        sm4[i] = make_float4(0.f, 0.f, 0.f, 0.f);
    __syncthreads();

    const float* fxp = flow + (size_t)b * 2 * HWc;
    const float* fyp = fxp + HWc;
    const float* dp  = depth + (size_t)b * HWc;

    // splat: 8 iterations; each thread owns a fixed 4-pixel column group and
    // walks 16 rows/iter. float4 loads; 1-deep register prefetch pipeline.
    const int gx  = rx0 + ((tid & 31) << 2);       // group start (4-aligned)
    const bool xok = (unsigned)gx < (unsigned)WW;  // groups fully in/out in x
    const bool xin = (unsigned)(gx - X0) < (unsigned)TILE;
    int gy = ry0 + (tid >> 5);
    float4 cfx, cfy, cd;
    bool ok = xok && ((unsigned)gy < (unsigned)HH);
    if (ok) {
        int p = gy * WW + gx;
        cfx = *(const float4*)(fxp + p);
        cfy = *(const float4*)(fyp + p);
        cd  = *(const float4*)(dp + p);
    }
#pragma unroll
    for (int k = 0; k < 8; ++k) {
        float4 nfx, nfy, nd;
        bool nok = false;
        const int ngy = gy + 16;
        if (k < 7) {
            nok = xok && ((unsigned)ngy < (unsigned)HH);
            if (nok) {
                int np = ngy * WW + gx;
                nfx = *(const float4*)(fxp + np);
                nfy = *(const float4*)(fyp + np);
                nd  = *(const float4*)(dp + np);
            }
        }
        if (ok) {
            const float gyf = (float)gy;
            const bool core = xin && ((unsigned)(gy - Y0) < (unsigned)TILE);
            PROC(cfx.x, cfy.x, cd.x, gx)
            PROC(cfx.y, cfy.y, cd.y, gx + 1)
            PROC(cfx.z, cfy.z, cd.z, gx + 2)
            PROC(cfx.w, cfy.w, cd.w, gx + 3)
        }
        ok = nok; gy = ngy; cfx = nfx; cfy = nfy; cd = nd;
    }
    __syncthreads();

    // writeback: 2x2 box of S per output cell, divide, store out planes +
    // w-plane + byte mask. Exclusive — no atomics, no merge.
    float* o0 = out + (size_t)b * 2 * HWc;
    float* o1 = o0 + HWc;
    float* wp = wplane + (size_t)b * HWc;
    unsigned char* mb = mask + (size_t)b * HWc;
#pragma unroll
    for (int k = 0; k < 2; ++k) {              // 1024 float4 groups / 512 threads
        int j   = k * 512 + tid;               // cell group: cells 4j..4j+3
        int row = j >> 4;                      // core row 0..63
        int gy2 = Y0 + row;
        if (gy2 < HH) {
            int c0 = (j & 15) << 2;            // core col of lane .x
            int q  = gy2 * WW + X0 + c0;
            const int rA = (row + 1) * SSTR + c0;   // S[row+1][c0 ..]
            const int rB = row * SSTR + c0;         // S[row  ][c0 ..]
            float4 vx, vy, wv;
            {
                float a_0 = sm[rA], a_1 = sm[rA+1], a_2 = sm[rA+2], a_3 = sm[rA+3], a_4 = sm[rA+4];
                float b_0 = sm[rB], b_1 = sm[rB+1], b_2 = sm[rB+2], b_3 = sm[rB+3], b_4 = sm[rB+4];
                vx.x = a_0+a_1+b_0+b_1; vx.y = a_1+a_2+b_1+b_2;
                vx.z = a_2+a_3+b_2+b_3; vx.w = a_3+a_4+b_3+b_4;
            }
            {
                const int oA = rA + PL, oB = rB + PL;
                float a_0 = sm[oA], a_1 = sm[oA+1], a_2 = sm[oA+2], a_3 = sm[oA+3], a_4 = sm[oA+4];
                float b_0 = sm[oB], b_1 = sm[oB+1], b_2 = sm[oB+2], b_3 = sm[oB+3], b_4 = sm[oB+4];
                vy.x = a_0+a_1+b_0+b_1; vy.y = a_1+a_2+b_1+b_2;
                vy.z = a_2+a_3+b_2+b_3; vy.w = a_3+a_4+b_3+b_4;
            }
            {
                const int oA = rA + 2 * PL, oB = rB + 2 * PL;
                float a_0 = sm[oA], a_1 = sm[oA+1], a_2 = sm[oA+2], a_3 = sm[oA+3], a_4 = sm[oA+4];
                float b_0 = sm[oB], b_1 = sm[oB+1], b_2 = sm[oB+2], b_3 = sm[oB+3], b_4 = sm[oB+4];
                wv.x = a_0+a_1+b_0+b_1; wv.y = a_1+a_2+b_1+b_2;
                wv.z = a_2+a_3+b_2+b_3; wv.w = a_3+a_4+b_3+b_4;
            }
            float i0 = wv.x > 0.f ? 1.f / wv.x : 0.f;
            float i1 = wv.y > 0.f ? 1.f / wv.y : 0.f;
            float i2 = wv.z > 0.f ? 1.f / wv.z : 0.f;
            float i3 = wv.w > 0.f ? 1.f / wv.w : 0.f;
            float4 r0, r1;
            r0.x = vx.x * i0; r0.y = vx.y * i1; r0.z = vx.z * i2; r0.w = vx.w * i3;
            r1.x = vy.x * i0; r1.y = vy.y * i1; r1.z = vy.z * i2; r1.w = vy.w * i3;
            *(float4*)(o0 + q) = r0;
            *(float4*)(o1 + q) = r1;
            *(float4*)(wp + q) = wv;           // for fixup_k renormalization
            uchar4 mk;
            mk.x = (unsigned char)(wv.x > 0.f);
            mk.y = (unsigned char)(wv.y > 0.f);
            mk.z = (unsigned char)(wv.z > 0.f);
            mk.w = (unsigned char)(wv.w > 0.f);
            *(uchar4*)(mb + q) = mk;           // q % 4 == 0 by construction
        }
    }
}

// ---------------------------------------------------------------------------
// Fixup v2, record-driven: O(n) per block, not O(4096). Most tiles have ~4
// records; n <= CAP = 256 = blockDim -> one record per thread.
//  A: plain-store 0 to each record's 3 LDS slots (duplicates benign)
//  B: atomicAdd record into slots
//  C: claim each touched cell via atomicExch(sw,0) — claimant (ws!=0) does
//     the exact renorm out_new = (out_old*w0 + sum_v)/(w0 + sum_w), sets mask.
// Records' w > 0 always (depth > 0.1), so ws != 0 identifies the claimant.
// ---------------------------------------------------------------------------
__global__ __launch_bounds__(256) void fixup_k(const unsigned* __restrict__ cnt,
                                               const float4* __restrict__ buckets,
                                               float* __restrict__ out,
                                               const float* __restrict__ wplane,
                                               unsigned char* __restrict__ mask) {
    __shared__ float s[3 * 4096];      // 48 KB (touched slots only are used)
    int gtile = blockIdx.x;
    unsigned n = cnt[gtile];
    if (n == 0) return;                // block-uniform, before any barrier
    if (n > (unsigned)CAP) n = CAP;
    int b  = gtile / NTILE;
    int t  = gtile - b * NTILE;
    int ty = t / WT, tx = t - ty * WT;
    int X0 = tx * TILE, Y0 = ty * TILE;

    const unsigned tid = threadIdx.x;
    const float4* bkt = buckets + (size_t)gtile * CAP;

    float4 rec;
    int cell = -1;
    if (tid < n) {
        rec  = bkt[tid];
        cell = __float_as_int(rec.x) & 4095;
        s[cell] = 0.f; s[cell + 4096] = 0.f; s[cell + 8192] = 0.f;
    }
    __syncthreads();
    if (tid < n) {
        atomicAdd(&s[cell],        rec.y);
        atomicAdd(&s[cell + 4096], rec.z);
        atomicAdd(&s[cell + 8192], rec.w);
    }
    __syncthreads();
    if (tid < n) {
        float ws = atomicExch(&s[cell + 8192], 0.f);
        if (ws > 0.f) {                // this thread owns the cell's renorm
            int cy = Y0 + (cell >> 6), cx = X0 + (cell & 63);
            if (cy < HH) {
                float* o0 = out + (size_t)b * 2 * HWc;
                float* o1 = o0 + HWc;
                int q = cy * WW + cx;
                float w0 = wplane[(size_t)b * HWc + q];
                float wn = w0 + ws;
                float v0 = o0[q] * w0 + s[cell];
                float v1 = o1[q] * w0 + s[cell + 4096];
                float inv = 1.f / wn;  // wn >= ws > 0
                o0[q] = v0 * inv;
                o1[q] = v1 * inv;
                mask[(size_t)b * HWc + q] = 1;
            }
        }
    }
}

// ---------------------------------------------------------------------------
// Hole fill, LDS-windowed (R7-proven): one block per 64x64 core, stage the
// 128x128 mask window, scan in LDS; exact global fallback for exhausted
// scans (P ~ 0.02^32, preserves reference semantics incl. borders).
// ---------------------------------------------------------------------------
constexpr int FWW = 128;               // fill window side
__global__ __launch_bounds__(256) void fill_k(float* __restrict__ out,
                                              const unsigned char* __restrict__ mask) {
    __shared__ unsigned char wm[FWW * FWW];    // 16 KB
    const int bid  = blockIdx.x;
    const int b    = bid & 7;
    const int tile = bid >> 3;
    const int ty   = tile / WT;
    const int tx   = tile - ty * WT;
    const int X0 = tx * TILE, Y0 = ty * TILE;
    const int wx0 = X0 - 32, wy0 = Y0 - 32;
    const int tid = threadIdx.x;

    const unsigned char* mb = mask + (size_t)b * HWc;

    // stage window: thread -> (row r = tid>>1, 64B half h = tid&1)
    {
        int r  = tid >> 1, h = tid & 1;
        int wy = wy0 + r;
        int xs = wx0 + h * 64;                 // multiple of 32 -> 16B aligned
        unsigned char* dst = &wm[r * FWW + h * 64];
        if ((unsigned)wy >= (unsigned)HH) {
            uint4 z = make_uint4(0u, 0u, 0u, 0u);
            uint4* d4 = (uint4*)dst;
            d4[0] = z; d4[1] = z; d4[2] = z; d4[3] = z;
        } else if (xs >= 0 && xs + 64 <= WW) {
            const uint4* s4 = (const uint4*)(mb + (size_t)wy * WW + xs);
            uint4* d4 = (uint4*)dst;
            d4[0] = s4[0]; d4[1] = s4[1]; d4[2] = s4[2]; d4[3] = s4[3];
        } else {
            for (int i = 0; i < 64; ++i) {
                int gxx = xs + i;
                dst[i] = ((unsigned)gxx < (unsigned)WW)
                             ? mb[(size_t)wy * WW + gxx] : (unsigned char)0;
            }
        }
    }
    __syncthreads();

    const float* o0 = out + (size_t)b * 2 * HWc;
    const float* o1 = o0 + HWc;

    // 4096 core pixels / 256 threads = 16 each; wave-aligned rows.
    for (int k = 0; k < 16; ++k) {
        int ci = k * 256 + tid;
        int ry = ci >> 6, cx = ci & 63;
        int gy = Y0 + ry;
        if (gy >= HH) continue;
        int wr = ry + 32, wc = cx + 32;
        if (wm[wr * FWW + wc]) continue;       // filled -> skip

        int gxp = X0 + cx;
        float s = 0.f, s0 = 0.f, s1 = 0.f;

        // LEFT
        {
            int f = -1;
            for (int j = wc - 1; j >= 0; --j)
                if (wm[wr * FWW + j]) { f = wx0 + j; break; }
            if (f < 0 && wx0 > 0)              // exhausted window (rare)
                for (int j = wx0 - 1; j >= 0; --j)
                    if (mb[(size_t)gy * WW + j]) { f = j; break; }
            if (f >= 0) { int q = gy * WW + f; s += 1.f; s0 += o0[q]; s1 += o1[q]; }
        }
        // RIGHT (window zero-padded beyond WW -> pad never matches)
        {
            int f = -1;
            for (int j = wc + 1; j < FWW; ++j)
                if (wm[wr * FWW + j]) { f = wx0 + j; break; }
            if (f < 0 && wx0 + FWW < WW)
                for (int j = wx0 + FWW; j < WW; ++j)
                    if (mb[(size_t)gy * WW + j]) { f = j; break; }
            if (f >= 0) { int q = gy * WW + f; s += 1.f; s0 += o0[q]; s1 += o1[q]; }
        }
        // UP
        {
            int f = -1;
            for (int i = wr - 1; i >= 0; --i)
                if (wm[i * FWW + wc]) { f = wy0 + i; break; }
            if (f < 0 && wy0 > 0)
                for (int i = wy0 - 1; i >= 0; --i)
                    if (mb[(size_t)i * WW + gxp]) { f = i; break; }
            if (f >= 0) { int q = f * WW + gxp; s += 1.f; s0 += o0[q]; s1 += o1[q]; }
        }
        // DOWN (window zero-padded beyond HH -> pad never matches)
        {
            int f = -1;
            for (int i = wr + 1; i < FWW; ++i)
                if (wm[i * FWW + wc]) { f = wy0 + i; break; }
            if (f < 0 && wy0 + FWW < HH)
                for (int i = wy0 + FWW; i < HH; ++i)
                    if (mb[(size_t)i * WW + gxp]) { f = i; break; }
            if (f >= 0) { int q = f * WW + gxp; s += 1.f; s0 += o0[q]; s1 += o1[q]; }
        }

        if (s > 0.f) {
            int p = gy * WW + gxp;
            ((float*)o0)[p] = s0 / s;
            ((float*)o1)[p] = s1 / s;
        }
    }
}

extern "C" void kernel_launch(void* const* d_in, const int* in_sizes, int n_in,
                              void* d_out, int out_size, void* d_ws, size_t ws_size,
                              hipStream_t stream) {
    const float* flow  = (const float*)d_in[0];   // (B,2,H,W)
    const float* depth = (const float*)d_in[1];   // (B,1,H,W)
    float* out = (float*)d_out;                   // (B,2,H,W)

    unsigned char* wsb = (unsigned char*)d_ws;
    unsigned* cnt       = (unsigned*)wsb;
    float4*  buckets    = (float4*)(wsb + OFF_BKT);
    unsigned char* mask = wsb + OFF_MASK;
    float*   wplane     = (float*)(wsb + OFF_W);

    const int threads = 256;

    // only memset: 16 KB of spill counters
    hipMemsetAsync(cnt, 0, (size_t)GT * sizeof(unsigned), stream);

    // fused: splat + spill discovery + average + mask/w-plane
    tile_k<<<GT, 512, 0, stream>>>(flow, depth, cnt, buckets, out, mask, wplane);

    // merge rare spill records, record-driven (must precede fill_k)
    fixup_k<<<GT, threads, 0, stream>>>(cnt, buckets, out, wplane, mask);

    // LDS-windowed hole fill
    fill_k<<<GT, threads, 0, stream>>>(out, mask);
}